// Round 5
// baseline (478.086 us; speedup 1.0000x reference)
//
#include <hip/hip_runtime.h>

// Circular-pad 3x3 conv, 1 -> 64 channels, fp32.
//   out[b,c,y,x] = bias[c] + sum_{r,s} w[c,0,r,s] * in[b,0,(y-1+r)%600,(x-1+s)%600]
//
// Ledger: conv stuck at ~137us (2.7 TB/s effective) in the (b,y,x)-thread /
// c-loop structure regardless of NT-vs-plain (v3) and store depth (v5);
// per-block sequential band sweeps were WORSE (v4, ~1.9 TB/s). The 6.25 TB/s
// fill's remaining untested signature is its globally-advancing COMPACT
// address front: at any instant the whole device writes one small window
// that sweeps memory monotonically.
//
// v6: test that cleanly. Persistent grid-stride blocks (2048x256, weights
// staged in LDS ONCE), flat item = 8-float segment in output memory order.
// Each sweep step the device covers a contiguous ~16 MB window -> DRAM page
// hits like the fill. Input is re-read per channel, but every block is in
// the same plane window at the same time -> the single relevant 1.44 MB
// input image is L2/L1-hot; per-iteration read cost is ~12 wave-loads
// (~18us of L1 beats chipwide). No per-block overhead (v2's confound).

typedef float v4f __attribute__((ext_vector_type(4)));

#define Bn 4
#define Cn 64
#define Hn 600
#define Wn 600
#define HW (Hn * Wn)
#define Pn (Bn * Cn)              // 256 output planes
#define SEG 8                     // floats per item (600 % 8 == 0 -> no row straddle)
#define SPR (Wn / SEG)            // 75 segments per row
#define SPP (Hn * SPR)            // 45000 segments per plane
#define NSEG (Pn * SPP)           // 11,520,000 items
#define NBLK 2048
#define NTHR (NBLK * 256)         // 524,288 threads -> 22 grid-stride steps

__global__ __launch_bounds__(256) void conv3x3_circ_kernel(
    const float* __restrict__ x,
    const float* __restrict__ w,
    const float* __restrict__ bias,
    float* __restrict__ out)
{
    // Weights+bias staged once per persistent block; 12 floats/channel so a
    // channel reads as 3 aligned float4 (wave-uniform address -> broadcast,
    // except the ~1/700 waves straddling a plane boundary: 2-way, free).
    __shared__ float lw[Cn * 12];
    const int tid = threadIdx.x;
    for (int idx = tid; idx < Cn * 12; idx += 256) {
        const int c = idx / 12;
        const int k = idx - c * 12;
        float v = 0.0f;
        if (k < 9)       v = w[c * 9 + k];
        else if (k == 9) v = bias[c];
        lw[idx] = v;
    }
    __syncthreads();
    const v4f* lw4 = (const v4f*)lw;

    for (int item = blockIdx.x * 256 + tid; item < NSEG; item += NTHR) {
        // item -> (plane p, row y, segment s); compile-time divisors -> magic mul.
        const int p  = item / SPP;
        const int r  = item - p * SPP;
        const int y  = r / SPR;
        const int s  = r - y * SPR;
        const int c  = p & (Cn - 1);
        const int b  = p >> 6;
        const int x0 = s * SEG;

        // Circular neighbor indices (edges only).
        const int ym = (y == 0)         ? (Hn - 1) : (y - 1);
        const int yp = (y == Hn - 1)    ? 0        : (y + 1);
        const int xm = (x0 == 0)        ? (Wn - 1) : (x0 - 1);
        const int xp = (x0 + SEG == Wn) ? 0        : (x0 + SEG);

        const float* xb = x + (size_t)b * HW;
        const float* rm = xb + ym * Wn;
        const float* rc = xb + y  * Wn;
        const float* rp = xb + yp * Wn;

        // 3 rows x 10 columns (x0-1 .. x0+8); all L1/L2-hot.
        float r0[10], r1[10], r2[10];
        v4f m0, m1;
        r0[0] = rm[xm]; m0 = *(const v4f*)(rm + x0); m1 = *(const v4f*)(rm + x0 + 4);
        r0[1] = m0.x; r0[2] = m0.y; r0[3] = m0.z; r0[4] = m0.w;
        r0[5] = m1.x; r0[6] = m1.y; r0[7] = m1.z; r0[8] = m1.w; r0[9] = rm[xp];
        r1[0] = rc[xm]; m0 = *(const v4f*)(rc + x0); m1 = *(const v4f*)(rc + x0 + 4);
        r1[1] = m0.x; r1[2] = m0.y; r1[3] = m0.z; r1[4] = m0.w;
        r1[5] = m1.x; r1[6] = m1.y; r1[7] = m1.z; r1[8] = m1.w; r1[9] = rc[xp];
        r2[0] = rp[xm]; m0 = *(const v4f*)(rp + x0); m1 = *(const v4f*)(rp + x0 + 4);
        r2[1] = m0.x; r2[2] = m0.y; r2[3] = m0.z; r2[4] = m0.w;
        r2[5] = m1.x; r2[6] = m1.y; r2[7] = m1.z; r2[8] = m1.w; r2[9] = rp[xp];

        const v4f wA = lw4[c * 3 + 0];  // w00 w01 w02 w10
        const v4f wB = lw4[c * 3 + 1];  // w11 w12 w20 w21
        const v4f wC = lw4[c * 3 + 2];  // w22 bias pad pad

        v4f o0, o1;
        #pragma unroll
        for (int j = 0; j < 4; ++j) {
            float a = wC.y;  // bias
            a += wA.x * r0[j] + wA.y * r0[j + 1] + wA.z * r0[j + 2];
            a += wA.w * r1[j] + wB.x * r1[j + 1] + wB.y * r1[j + 2];
            a += wB.z * r2[j] + wB.w * r2[j + 1] + wC.x * r2[j + 2];
            o0[j] = a;
        }
        #pragma unroll
        for (int j = 0; j < 4; ++j) {
            float a = wC.y;
            a += wA.x * r0[j + 4] + wA.y * r0[j + 5] + wA.z * r0[j + 6];
            a += wA.w * r1[j + 4] + wB.x * r1[j + 5] + wB.y * r1[j + 6];
            a += wB.z * r2[j + 4] + wB.w * r2[j + 5] + wC.x * r2[j + 6];
            o1[j] = a;
        }

        float* op = out + (size_t)p * HW + (size_t)y * Wn + x0;
        *(v4f*)op       = o0;
        *(v4f*)(op + 4) = o1;
    }
}

extern "C" void kernel_launch(void* const* d_in, const int* in_sizes, int n_in,
                              void* d_out, int out_size, void* d_ws, size_t ws_size,
                              hipStream_t stream) {
    const float* x    = (const float*)d_in[0];   // (4,1,600,600)
    const float* w    = (const float*)d_in[1];   // (64,1,3,3)
    const float* bias = (const float*)d_in[2];   // (64,)
    float* out        = (float*)d_out;           // (4,64,600,600)

    conv3x3_circ_kernel<<<NBLK, 256, 0, stream>>>(x, w, bias, out);
}

// Round 6
// 375.270 us; speedup vs baseline: 1.2740x; 1.2740x over previous
//
#include <hip/hip_runtime.h>

// Circular-pad 3x3 conv, 1 -> 64 channels, fp32.
//   out[b,c,y,x] = bias[c] + sum_{r,s} w[c,0,r,s] * in[b,0,(y-1+r)%600,(x-1+s)%600]
//
// v7 = v1 (best measured: 370.3 us) + bijective XCD-chunked block swizzle.
// Ledger of falsified write-side levers (all A/B'd on hardware):
//   - NT vs plain store: neutral (v1 370.3 / v3 373.5)
//   - per-wave store depth 4 -> 16: neutral (v5 374.6)
//   - per-block sequential plane sweeps: WORSE (v4, conv +100us)
//   - globally compact advancing write front: WORSE (v6, conv +105us)
//   - any structure re-reading input per channel: +~100us of L1 read beats
// Structure: one thread per (b, y, 4-wide x group); 3x6 input neighborhood
// loaded once into registers, reused across all 64 channels; weights+bias
// staged once in LDS (wave-uniform b128 broadcasts); one 1KB-per-wave
// nontemporal float4 store per channel.
// v7's single variable: XCD k owns a contiguous 1/8 chunk of the block range
// (grid padded to 1408 = 176*8 for bijectivity) -> each XCD's L2 handles
// contiguous y-bands instead of stride-8 interleaved rows.

typedef float v4f __attribute__((ext_vector_type(4)));

#define Bn 4
#define Cn 64
#define Hn 600
#define Wn 600
#define Gn (Wn / 4)              // 150 float4 groups per row
#define TOTAL (Bn * Hn * Gn)     // 360000 threads
#define NBLK 1408                // padded to a multiple of 8 (last block idles)
#define CPX (NBLK / 8)           // 176 blocks per XCD chunk

__global__ __launch_bounds__(256) void conv3x3_circ_kernel(
    const float* __restrict__ x,
    const float* __restrict__ w,
    const float* __restrict__ bias,
    float* __restrict__ out)
{
    // Stage weights+bias in LDS, padded to 12 floats per channel so each
    // channel reads as 3 aligned float4 (wave-uniform address -> broadcast).
    __shared__ float lw[Cn * 12];
    const int tid = threadIdx.x;
    for (int idx = tid; idx < Cn * 12; idx += 256) {
        const int c = idx / 12;
        const int k = idx - c * 12;
        float v = 0.0f;
        if (k < 9)       v = w[c * 9 + k];
        else if (k == 9) v = bias[c];
        lw[idx] = v;
    }
    __syncthreads();

    // Bijective XCD-chunked swizzle (NBLK % 8 == 0): XCD k gets blocks
    // [k*CPX, (k+1)*CPX) = contiguous (b, y) bands.
    const int bid = blockIdx.x;
    const int swz = (bid & 7) * CPX + (bid >> 3);

    const int i = swz * 256 + tid;
    if (i >= TOTAL) return;

    const int g  = i % Gn;
    const int t  = i / Gn;
    const int y  = t % Hn;
    const int b  = t / Hn;
    const int x0 = g * 4;

    // Circular neighbor indices (branch-free selects; only edges differ).
    const int ym = (y == 0)        ? (Hn - 1) : (y - 1);
    const int yp = (y == Hn - 1)   ? 0        : (y + 1);
    const int xm = (x0 == 0)       ? (Wn - 1) : (x0 - 1);
    const int xp = (x0 + 4 == Wn)  ? 0        : (x0 + 4);

    const float* xb = x + (size_t)b * (Hn * Wn);
    const float* rm = xb + ym * Wn;
    const float* rc = xb + y  * Wn;
    const float* rp = xb + yp * Wn;

    // 3 rows x 6 columns of input (cols x0-1 .. x0+4), loaded once,
    // reused across all 64 output channels.
    float r0[6], r1[6], r2[6];
    v4f m;
    r0[0] = rm[xm]; m = *(const v4f*)(rm + x0);
    r0[1] = m.x; r0[2] = m.y; r0[3] = m.z; r0[4] = m.w; r0[5] = rm[xp];
    r1[0] = rc[xm]; m = *(const v4f*)(rc + x0);
    r1[1] = m.x; r1[2] = m.y; r1[3] = m.z; r1[4] = m.w; r1[5] = rc[xp];
    r2[0] = rp[xm]; m = *(const v4f*)(rp + x0);
    r2[1] = m.x; r2[2] = m.y; r2[3] = m.z; r2[4] = m.w; r2[5] = rp[xp];

    float* op = out + (size_t)b * (Cn * Hn * Wn) + (size_t)y * Wn + x0;
    const v4f* lw4 = (const v4f*)lw;

    #pragma unroll 4
    for (int c = 0; c < Cn; ++c) {
        const v4f wA = lw4[c * 3 + 0];  // w00 w01 w02 w10
        const v4f wB = lw4[c * 3 + 1];  // w11 w12 w20 w21
        const v4f wC = lw4[c * 3 + 2];  // w22 bias pad pad
        v4f o;
        #pragma unroll
        for (int j = 0; j < 4; ++j) {
            float a = wC.y;  // bias
            a += wA.x * r0[j] + wA.y * r0[j + 1] + wA.z * r0[j + 2];
            a += wA.w * r1[j] + wB.x * r1[j + 1] + wB.y * r1[j + 2];
            a += wB.z * r2[j] + wB.w * r2[j + 1] + wC.x * r2[j + 2];
            o[j] = a;
        }
        // Output is write-once, never re-read (NT vs plain proven neutral;
        // keep NT to match the best-measured configuration exactly).
        __builtin_nontemporal_store(o, (v4f*)op);
        op += Hn * Wn;  // next channel plane
    }
}

extern "C" void kernel_launch(void* const* d_in, const int* in_sizes, int n_in,
                              void* d_out, int out_size, void* d_ws, size_t ws_size,
                              hipStream_t stream) {
    const float* x    = (const float*)d_in[0];   // (4,1,600,600)
    const float* w    = (const float*)d_in[1];   // (64,1,3,3)
    const float* bias = (const float*)d_in[2];   // (64,)
    float* out        = (float*)d_out;           // (4,64,600,600)

    conv3x3_circ_kernel<<<NBLK, 256, 0, stream>>>(x, w, bias, out);
}